// Round 3
// baseline (408.590 us; speedup 1.0000x reference)
//
#include <hip/hip_runtime.h>

typedef unsigned short ushort_t;
typedef unsigned int uint_t;
typedef __bf16 bf16x8 __attribute__((ext_vector_type(8)));
typedef float f32x4 __attribute__((ext_vector_type(4)));

#define B_ROWS 65536

// Tile geometry: one MFMA tile = 16 rows x 32 k of bf16 = 1024 B = 512 ushorts.
// Unit l (0..63) within a tile <-> (row = l&15, k = (l>>4)*8 .. +8).
#define KT1 12    // x' k-tiles   (K 376 -> 384)
#define NT1 30    // K1 n-tiles   (N 400 -> 480)
#define KTC1 15   // h1' k-tiles  (480/32)
#define KI2 13    // K2 k-iters   (K 400 -> 416)
#define NT2 20    // K2 n-tiles   (N 320)
#define KTC2 10   // h2' k-tiles  (320/32)
#define KI3 10    // K3 k-iters   (320/32)
#define NT3 50    // K3 n-tiles   (N 800: aligned head layout)
#define KTH 25    // heads' row-stride in ktiles (800/32)

// Aligned head layout (all slots on 8-col boundaries; pads are exact zeros):
//  [0:24)  mu (17 real)   groups 0..2
//  [24:48) lv (17 real)   groups 3..5
//  [48:64) b  (15 real)   groups 6..7
//  [64+48k : +24)  u_k (17 real)  groups 8+6k .. +2
//  [64+48k+24 : +48) w_k (17 real) groups 11+6k .. +2

#define SZ1 (NT1 * KT1 * 512)
#define SZ2 (NT2 * KI2 * 512)
#define SZ3 (NT3 * KI3 * 512)

// LDS pools (ushort units), per 64-row strip:
//  P_X  [0,      24576)  x'  4 rowtiles x 12 ktiles (48 KB)
//  P_H1 [24576,  55296)  h1' 4 x 15 (60 KB)
//  P_H2 [55296,  75776)  h2' 4 x 10 (40 KB)
//  P_HD [0,      51200)  heads 4 x 25 (100 KB) -- overlays P_X+P_H1 (dead by K3)
#define P_X  0
#define P_H1 24576
#define P_H2 55296
#define P_HD 0
#define SM_TOT 75776   // 151552 B static LDS (<= 160 KB/CU, 1 block/CU)

__device__ inline ushort_t f2bf(float f) {
    uint_t u = __float_as_uint(f);
    return (ushort_t)((u + 0x7FFFu + ((u >> 16) & 1u)) >> 16);
}
__device__ inline uint_t pack2(float a, float b) {
    return (uint_t)f2bf(a) | ((uint_t)f2bf(b) << 16);
}
__device__ inline float fast_tanh(float x) {
    float e = __expf(2.f * x);
    return 1.f - 2.f / (e + 1.f);
}
__device__ inline void unpack8(uint4 v, float* dst) {
    uint_t q[4] = {v.x, v.y, v.z, v.w};
    #pragma unroll
    for (int m = 0; m < 4; ++m) {
        dst[2 * m]     = __uint_as_float(q[m] << 16);          // low bf16
        dst[2 * m + 1] = __uint_as_float(q[m] & 0xFFFF0000u);  // high bf16
    }
}

// ---------------------------------------------------------------------------
// pack_kernel: fp32 weights -> MFMA-tile-order bf16 + zero-padded fp32 biases.
// ---------------------------------------------------------------------------
__global__ void pack_kernel(const float* __restrict__ W1, const float* __restrict__ W2,
                            const float* __restrict__ Wmu, const float* __restrict__ Wlv,
                            const float* __restrict__ Wu, const float* __restrict__ Ww,
                            const float* __restrict__ Wb,
                            const float* __restrict__ b1, const float* __restrict__ b2,
                            const float* __restrict__ bmu, const float* __restrict__ blv,
                            const float* __restrict__ bu, const float* __restrict__ bw,
                            const float* __restrict__ bb,
                            ushort_t* __restrict__ W1t, ushort_t* __restrict__ W2t,
                            ushort_t* __restrict__ Wht,
                            float* __restrict__ b1p, float* __restrict__ b2p,
                            float* __restrict__ bHp)
{
    int i = blockIdx.x * 256 + threadIdx.x;
    if (i < SZ1) {
        int t = i >> 9, pos = i & 511;
        int l = pos >> 3, j = pos & 7;
        int n = (t / KT1) * 16 + (l & 15);
        int k = (t % KT1) * 32 + (l >> 4) * 8 + j;
        W1t[i] = (n < 400 && k < 376) ? f2bf(W1[k * 400 + n]) : (ushort_t)0;
    } else if (i < SZ1 + SZ2) {
        int i2 = i - SZ1;
        int t = i2 >> 9, pos = i2 & 511;
        int l = pos >> 3, j = pos & 7;
        int n = (t / KI2) * 16 + (l & 15);
        int k = (t % KI2) * 32 + (l >> 4) * 8 + j;
        W2t[i2] = (n < 300 && k < 400) ? f2bf(W2[k * 300 + n]) : (ushort_t)0;
    } else if (i < SZ1 + SZ2 + SZ3) {
        int i3 = i - SZ1 - SZ2;
        int t = i3 >> 9, pos = i3 & 511;
        int l = pos >> 3, j = pos & 7;
        int n = (t / KI3) * 16 + (l & 15);
        int k = (t % KI3) * 32 + (l >> 4) * 8 + j;
        float v = 0.f;
        if (k < 300) {
            if (n < 24)      { if (n < 17) v = Wmu[k * 17 + n]; }
            else if (n < 48) { int c = n - 24; if (c < 17) v = Wlv[k * 17 + c]; }
            else if (n < 64) { int c = n - 48; if (c < 15) v = Wb[k * 15 + c]; }
            else if (n < 784) {
                int r = n - 64, slot = r / 48, c = r % 48;
                if (c < 24) { if (c < 17) v = Wu[k * 255 + slot * 17 + c]; }
                else        { int c2 = c - 24; if (c2 < 17) v = Ww[k * 255 + slot * 17 + c2]; }
            }
        }
        Wht[i3] = f2bf(v);
    } else {
        int j = i - SZ1 - SZ2 - SZ3;
        if (j < 480) {
            b1p[j] = (j < 400) ? b1[j] : 0.f;
        } else if (j < 800) {
            int n = j - 480;
            b2p[n] = (n < 300) ? b2[n] : 0.f;
        } else if (j < 1600) {
            int n = j - 800;
            float v = 0.f;
            if (n < 24)      { if (n < 17) v = bmu[n]; }
            else if (n < 48) { int c = n - 24; if (c < 17) v = blv[c]; }
            else if (n < 64) { int c = n - 48; if (c < 15) v = bb[c]; }
            else if (n < 784) {
                int r = n - 64, slot = r / 48, c = r % 48;
                if (c < 24) { if (c < 17) v = bu[slot * 17 + c]; }
                else        { int c2 = c - 24; if (c2 < 17) v = bw[slot * 17 + c2]; }
            }
            bHp[n] = v;
        }
    }
}

// ---------------------------------------------------------------------------
// phase_gemm: one GEMM phase of the fused kernel.
//   A: LDS, tiled, 4 rowtiles with row-stride ktA ktiles (wave reads ALL 4).
//   B: global, tiled, NT ntiles x KITERS ktiles (L2-resident weights).
//   C: LDS, tiled, 4 rowtiles with row-stride ktC.
// Waves split N: wave wv owns ntiles [NT*wv/8, NT*(wv+1)/8) (max 7).
// Each B-frag load feeds 4 MFMAs (one per rowtile). No barriers inside.
// ---------------------------------------------------------------------------
template<int KITERS, bool RELU>
__device__ __forceinline__ void phase_gemm(
    ushort_t* sm, int aBase, int ktA,
    const ushort_t* __restrict__ Bt, const float* __restrict__ bias,
    int cBase, int ktC, int NT, int lane, int wv)
{
    const int n0 = (NT * wv) >> 3;
    const int cnt = ((NT * (wv + 1)) >> 3) - n0;

    f32x4 acc[4][7];
    #pragma unroll
    for (int rt = 0; rt < 4; ++rt)
        #pragma unroll
        for (int c = 0; c < 7; ++c)
            acc[rt][c] = (f32x4){0.f, 0.f, 0.f, 0.f};

    #pragma unroll
    for (int kt = 0; kt < KITERS; ++kt) {
        bf16x8 a[4];
        #pragma unroll
        for (int rt = 0; rt < 4; ++rt)
            a[rt] = __builtin_bit_cast(bf16x8, *reinterpret_cast<const uint4*>(
                &sm[aBase + ((rt * ktA + kt) << 9) + lane * 8]));
        #pragma unroll
        for (int c = 0; c < 7; ++c) {
            if (c < cnt) {   // wave-uniform branch -> scalar skip
                bf16x8 b = __builtin_bit_cast(bf16x8, *reinterpret_cast<const uint4*>(
                    Bt + (((size_t)(n0 + c) * KITERS + kt) << 9) + lane * 8));
                #pragma unroll
                for (int rt = 0; rt < 4; ++rt)
                    acc[rt][c] = __builtin_amdgcn_mfma_f32_16x16x32_bf16(
                        a[rt], b, acc[rt][c], 0, 0, 0);
            }
        }
    }

    // epilogue -> LDS C (tiled); C/D frag: col = lane&15, row = (lane>>4)*4+reg
    const int q = lane >> 4, l16 = lane & 15;
    #pragma unroll
    for (int c = 0; c < 7; ++c) {
        if (c < cnt) {
            int n = (n0 + c) * 16 + l16;
            float bv = bias[n];
            #pragma unroll
            for (int rt = 0; rt < 4; ++rt) {
                #pragma unroll
                for (int reg = 0; reg < 4; ++reg) {
                    float v = acc[rt][c][reg] + bv;
                    if (RELU) v = fmaxf(v, 0.f);
                    int r16 = q * 4 + reg;
                    sm[cBase + ((rt * ktC + (n >> 5)) << 9) + (((n >> 3) & 3) << 7)
                       + (r16 << 3) + (n & 7)] = f2bf(v);
                }
            }
        }
    }
}

// ---------------------------------------------------------------------------
// fused_kernel: one 64-row strip per block. 512 threads = 8 waves, 1 block/CU.
// Phases: x->x'(LDS) | K1 | K2 | K3 (heads->LDS) | planar flow (threads 0..255)
// Only HBM traffic: x read, eps read, out write, weights (L2-resident).
// ---------------------------------------------------------------------------
__global__ __launch_bounds__(512, 2)
void fused_kernel(const float* __restrict__ x, const float* __restrict__ eps,
                  const ushort_t* __restrict__ W1t, const ushort_t* __restrict__ W2t,
                  const ushort_t* __restrict__ Wht,
                  const float* __restrict__ b1p, const float* __restrict__ b2p,
                  const float* __restrict__ bHp,
                  float* __restrict__ out)
{
    __shared__ ushort_t sm[SM_TOT];
    const int tid = threadIdx.x;
    const int lane = tid & 63, wv = tid >> 6;
    const long row0 = (long)blockIdx.x * 64;

    // ---- phase 0: x (f32 row-major) -> x' (bf16 tiles) in LDS ----
    // unit u = row*48 + ku covers x[row][ku*8 .. +8); 64 rows x 48 units.
    #pragma unroll
    for (int it = 0; it < 6; ++it) {
        int u = it * 512 + tid;
        int row = u / 48, ku = u - row * 48;
        uint4 o = {0u, 0u, 0u, 0u};
        if (ku < 47) {   // 47*8 = 376 = real K
            const float4* p = reinterpret_cast<const float4*>(
                x + (row0 + row) * 376 + ku * 8);
            float4 v0 = p[0], v1 = p[1];
            o.x = pack2(v0.x, v0.y); o.y = pack2(v0.z, v0.w);
            o.z = pack2(v1.x, v1.y); o.w = pack2(v1.z, v1.w);
        }
        *reinterpret_cast<uint4*>(
            &sm[P_X + (((row >> 4) * KT1 + (ku >> 2)) << 9) + ((ku & 3) << 7)
                + ((row & 15) << 3)]) = o;
    }
    __syncthreads();

    // ---- K1: h1' = relu(x' @ W1^T + b1)   K=384, N=480 ----
    phase_gemm<KT1, true>(sm, P_X, KT1, W1t, b1p, P_H1, KTC1, NT1, lane, wv);
    __syncthreads();

    // ---- K2: h2' = relu(h1' @ W2^T + b2)  K=416, N=320 ----
    phase_gemm<KI2, true>(sm, P_H1, KTC1, W2t, b2p, P_H2, KTC2, NT2, lane, wv);
    __syncthreads();

    // ---- K3: heads = h2' @ Wh^T + bH      K=320, N=800 (overlays P_X+P_H1) ----
    phase_gemm<KI3, false>(sm, P_H2, KTC2, Wht, bHp, P_HD, KTH, NT3, lane, wv);
    __syncthreads();

    // ---- phase 4: planar flow from LDS heads; threads 0..255 = 64 rows x 4 ----
    if (tid < 256) {
        const int sub = tid & 3;
        const int row = tid >> 2;
        const int hb = P_HD + (((row >> 4) * KTH) << 9) + ((row & 15) << 3);
        const long grow = row0 + row;

        float z[8];
        float lp = 0.f;
        {
            float amu[8] = {0,0,0,0,0,0,0,0}, alv[8] = {0,0,0,0,0,0,0,0};
            if (sub < 3) {
                unpack8(*reinterpret_cast<const uint4*>(
                    &sm[hb + ((sub >> 2) << 9) + ((sub & 3) << 7)]), amu);
                int g = 3 + sub;
                unpack8(*reinterpret_cast<const uint4*>(
                    &sm[hb + ((g >> 2) << 9) + ((g & 3) << 7)]), alv);
            }
            float ep[8];
            #pragma unroll
            for (int c = 0; c < 8; ++c) {
                int i = sub * 8 + c;
                ep[c] = (i < 17) ? eps[grow * 17 + i] : 0.f;
            }
            #pragma unroll
            for (int c = 0; c < 8; ++c) {
                float mu = fast_tanh(amu[c]);
                float lv = fast_tanh(alv[c]);
                z[c] = mu + __expf(lv) * ep[c];
                int i = sub * 8 + c;
                lp += (i < 17) ? (-0.5f * ep[c] * ep[c] - lv - 0.918938533f) : 0.f;
            }
        }

        float bv[16];
        unpack8(*reinterpret_cast<const uint4*>(&sm[hb + 512 + 256]), &bv[0]);  // g=6
        unpack8(*reinterpret_cast<const uint4*>(&sm[hb + 512 + 384]), &bv[8]);  // g=7

        float ldj = 0.f;
        #pragma unroll
        for (int k = 0; k < 15; ++k) {
            float au[8] = {0,0,0,0,0,0,0,0}, aw[8] = {0,0,0,0,0,0,0,0};
            if (sub < 3) {
                int gu = 8 + 6 * k + sub;
                int gw = 11 + 6 * k + sub;
                unpack8(*reinterpret_cast<const uint4*>(
                    &sm[hb + ((gu >> 2) << 9) + ((gu & 3) << 7)]), au);
                unpack8(*reinterpret_cast<const uint4*>(
                    &sm[hb + ((gw >> 2) << 9) + ((gw & 3) << 7)]), aw);
            }
            float uw = 0.f, w2 = 0.f, wz = 0.f;
            #pragma unroll
            for (int c = 0; c < 8; ++c) {
                uw += aw[c] * au[c];
                w2 += aw[c] * aw[c];
                wz += aw[c] * z[c];
            }
            uw += __shfl_xor(uw, 1); uw += __shfl_xor(uw, 2);
            w2 += __shfl_xor(w2, 1); w2 += __shfl_xor(w2, 2);
            wz += __shfl_xor(wz, 1); wz += __shfl_xor(wz, 2);

            float sp = (uw > 15.f) ? uw : __logf(1.f + __expf(uw));
            float m = sp - 1.f;                          // -1 + softplus(w.u)
            float coef = (m - uw) / fmaxf(w2, 1e-20f);
            float t = fast_tanh(wz + bv[k]);
            #pragma unroll
            for (int c = 0; c < 8; ++c)
                z[c] += (au[c] + coef * aw[c]) * t;
            float psi = m * (1.f - t * t);               // psi^T u_hat == m analytically
            ldj += __logf(fmaxf(fabsf(1.f + psi), 1e-30f));
        }

        lp += __shfl_xor(lp, 1); lp += __shfl_xor(lp, 2);
        #pragma unroll
        for (int c = 0; c < 8; ++c) {
            int i = sub * 8 + c;
            if (i < 17) out[grow * 17 + i] = z[c];
        }
        float lpf = lp - ldj;
        if (sub == 0) {
            out[(long)B_ROWS * 17 + grow] = __expf(lpf);
            out[(long)B_ROWS * 18 + grow] = lpf;
        }
    }
}

// ---------------------------------------------------------------------------
extern "C" void kernel_launch(void* const* d_in, const int* in_sizes, int n_in,
                              void* d_out, int out_size, void* d_ws, size_t ws_size,
                              hipStream_t stream)
{
    const float* x   = (const float*)d_in[0];
    const float* eps = (const float*)d_in[1];
    float* out = (float*)d_out;

    // ws: only packed weights now (~1.2 MB)
    ushort_t* W1t = (ushort_t*)d_ws;
    ushort_t* W2t = W1t + SZ1;
    ushort_t* Wht = W2t + SZ2;
    float* b1p = (float*)(Wht + SZ3);
    float* b2p = b1p + 480;
    float* bHp = b2p + 320;

    const int packN = SZ1 + SZ2 + SZ3 + 1600;
    pack_kernel<<<(packN + 255) / 256, 256, 0, stream>>>(
        (const float*)d_in[2],  (const float*)d_in[4],
        (const float*)d_in[6],  (const float*)d_in[8],
        (const float*)d_in[10], (const float*)d_in[12], (const float*)d_in[14],
        (const float*)d_in[3],  (const float*)d_in[5],
        (const float*)d_in[7],  (const float*)d_in[9],
        (const float*)d_in[11], (const float*)d_in[13], (const float*)d_in[15],
        W1t, W2t, Wht, b1p, b2p, bHp);

    fused_kernel<<<B_ROWS / 64, 512, 0, stream>>>(
        x, eps, W1t, W2t, Wht, b1p, b2p, bHp, out);
}

// Round 4
// 343.222 us; speedup vs baseline: 1.1905x; 1.1905x over previous
//
#include <hip/hip_runtime.h>

typedef unsigned short ushort_t;
typedef unsigned int uint_t;
typedef __bf16 bf16x8 __attribute__((ext_vector_type(8)));
typedef float f32x4 __attribute__((ext_vector_type(4)));

#define B_ROWS 65536

// Tile geometry: one MFMA tile = 16 rows x 32 k of bf16 = 1024 B = 512 ushorts.
// Unit l (0..63) within a tile <-> (row = l&15, k = (l>>4)*8 .. +8).
#define KT1 12    // K1 k-iters  (K 376 -> 384)
#define NT1 30    // K1 n-tiles  (N 400 -> 480)
#define KTC1 15   // h1' k-tiles (480/32)
#define KI2 13    // K2 k-iters  (K 400 -> 416; h1' cols 400..480 are exact 0)
#define NT2 20    // K2 n-tiles  (N 320)
#define KTC2 10   // h2' k-tiles (320/32)
#define KI3 10    // K3 k-iters  (320/32)
#define NT3 50    // K3 n-tiles  (N 800: aligned head layout)
#define KTH 25    // heads' row-stride in ktiles (800/32)

// Aligned head layout (all slots on 8-col boundaries; pads are exact zeros):
//  [0:24)  mu (17 real)   groups 0..2
//  [24:48) lv (17 real)   groups 3..5
//  [48:64) b  (15 real)   groups 6..7
//  [64+48k : +24)  u_k (17 real)  groups 8+6k .. +2
//  [64+48k+24 : +48) w_k (17 real) groups 11+6k .. +2

#define SZ1 (NT1 * KT1 * 512)
#define SZ2 (NT2 * KI2 * 512)
#define SZ3 (NT3 * KI3 * 512)

// workspace (ushort units): [h2' 20.97M][h1' 31.46M -> overlaid by heads 52.43M][weights]
#define H2_US  ((size_t)4096 * KTC2 * 512)
#define HEADS_US ((size_t)4096 * KTH * 512)

__device__ inline ushort_t f2bf(float f) {
    uint_t u = __float_as_uint(f);
    return (ushort_t)((u + 0x7FFFu + ((u >> 16) & 1u)) >> 16);
}
__device__ inline uint_t pack2(float a, float b) {
    return (uint_t)f2bf(a) | ((uint_t)f2bf(b) << 16);
}
__device__ inline float fast_tanh(float x) {
    float e = __expf(2.f * x);
    return 1.f - 2.f / (e + 1.f);
}
// async global->LDS, 16 B per lane; LDS dest = wave-uniform base + lane*16
__device__ inline void gl2lds16(const ushort_t* g, ushort_t* l) {
    __builtin_amdgcn_global_load_lds(
        (const __attribute__((address_space(1))) uint_t*)g,
        (__attribute__((address_space(3))) uint_t*)l, 16, 0, 0);
}
__device__ inline void unpack8(uint4 v, float* dst) {
    uint_t q[4] = {v.x, v.y, v.z, v.w};
    #pragma unroll
    for (int m = 0; m < 4; ++m) {
        dst[2 * m]     = __uint_as_float(q[m] << 16);          // low bf16
        dst[2 * m + 1] = __uint_as_float(q[m] & 0xFFFF0000u);  // high bf16
    }
}

// ---------------------------------------------------------------------------
// pack_kernel: fp32 weights -> MFMA-tile-order bf16 + zero-padded fp32 biases.
// ---------------------------------------------------------------------------
__global__ void pack_kernel(const float* __restrict__ W1, const float* __restrict__ W2,
                            const float* __restrict__ Wmu, const float* __restrict__ Wlv,
                            const float* __restrict__ Wu, const float* __restrict__ Ww,
                            const float* __restrict__ Wb,
                            const float* __restrict__ b1, const float* __restrict__ b2,
                            const float* __restrict__ bmu, const float* __restrict__ blv,
                            const float* __restrict__ bu, const float* __restrict__ bw,
                            const float* __restrict__ bb,
                            ushort_t* __restrict__ W1t, ushort_t* __restrict__ W2t,
                            ushort_t* __restrict__ Wht,
                            float* __restrict__ b1p, float* __restrict__ b2p,
                            float* __restrict__ bHp)
{
    int i = blockIdx.x * 256 + threadIdx.x;
    if (i < SZ1) {
        int t = i >> 9, pos = i & 511;
        int l = pos >> 3, j = pos & 7;
        int n = (t / KT1) * 16 + (l & 15);
        int k = (t % KT1) * 32 + (l >> 4) * 8 + j;
        W1t[i] = (n < 400 && k < 376) ? f2bf(W1[k * 400 + n]) : (ushort_t)0;
    } else if (i < SZ1 + SZ2) {
        int i2 = i - SZ1;
        int t = i2 >> 9, pos = i2 & 511;
        int l = pos >> 3, j = pos & 7;
        int n = (t / KI2) * 16 + (l & 15);
        int k = (t % KI2) * 32 + (l >> 4) * 8 + j;
        W2t[i2] = (n < 300 && k < 400) ? f2bf(W2[k * 300 + n]) : (ushort_t)0;
    } else if (i < SZ1 + SZ2 + SZ3) {
        int i3 = i - SZ1 - SZ2;
        int t = i3 >> 9, pos = i3 & 511;
        int l = pos >> 3, j = pos & 7;
        int n = (t / KI3) * 16 + (l & 15);
        int k = (t % KI3) * 32 + (l >> 4) * 8 + j;
        float v = 0.f;
        if (k < 300) {
            if (n < 24)      { if (n < 17) v = Wmu[k * 17 + n]; }
            else if (n < 48) { int c = n - 24; if (c < 17) v = Wlv[k * 17 + c]; }
            else if (n < 64) { int c = n - 48; if (c < 15) v = Wb[k * 15 + c]; }
            else if (n < 784) {
                int r = n - 64, slot = r / 48, c = r % 48;
                if (c < 24) { if (c < 17) v = Wu[k * 255 + slot * 17 + c]; }
                else        { int c2 = c - 24; if (c2 < 17) v = Ww[k * 255 + slot * 17 + c2]; }
            }
        }
        Wht[i3] = f2bf(v);
    } else {
        int j = i - SZ1 - SZ2 - SZ3;
        if (j < 480) {
            b1p[j] = (j < 400) ? b1[j] : 0.f;
        } else if (j < 800) {
            int n = j - 480;
            b2p[n] = (n < 300) ? b2[n] : 0.f;
        } else if (j < 1600) {
            int n = j - 800;
            float v = 0.f;
            if (n < 24)      { if (n < 17) v = bmu[n]; }
            else if (n < 48) { int c = n - 24; if (c < 17) v = blv[c]; }
            else if (n < 64) { int c = n - 48; if (c < 15) v = bb[c]; }
            else if (n < 784) {
                int r = n - 64, slot = r / 48, c = r % 48;
                if (c < 24) { if (c < 17) v = bu[slot * 17 + c]; }
                else        { int c2 = c - 24; if (c2 < 17) v = bw[slot * 17 + c2]; }
            }
            bHp[n] = v;
        }
    }
}

// ---------------------------------------------------------------------------
// gemm_db: C' = act(A @ B^T + bias), double-buffered staging, one barrier/kt.
//   CVT_A=true : A read from f32 x (row-major, ld 376) with on-the-fly bf16
//                conversion (reg-staged ds_write). kt+1 loads issued before
//                kt's MFMAs -> latency hidden.
//   CVT_A=false: A read from tiled bf16 via global_load_lds (issued early).
//   B always via global_load_lds (L2-resident weights).
// BM=128 (8 rowtiles), BN=160 (10 ntiles), BK=32; 256 thr = 4 waves.
// XCD-bijective remap: all NX n-blocks of one rowblock land on one XCD so the
// A panel is fetched from HBM once and re-served by that XCD's L2.
// LDS 2*(8+10) KB = 36 KB -> 4 blocks/CU.
// ---------------------------------------------------------------------------
template<int KITERS, int NX, bool RELU, bool CVT_A>
__global__ __launch_bounds__(256)
void gemm_db(const ushort_t* __restrict__ At, const float* __restrict__ xf,
             const ushort_t* __restrict__ Bt, const float* __restrict__ bias,
             ushort_t* __restrict__ C, int kTA, int kTC)
{
    __shared__ ushort_t As[2][8 * 512];
    __shared__ ushort_t Bs[2][10 * 512];
    const int tid = threadIdx.x;
    const int lane = tid & 63, wv = tid >> 6;
    const int q = lane >> 4, l16 = lane & 15;

    // bijective XCD remap (gridDim.x = NX*512; 512 % 8 == 0)
    const int b = blockIdx.x;
    const int xcd = b & 7, idx = b >> 3;
    const int grp = idx / NX;
    const int bx = idx - grp * NX;
    const int by = xcd + grp * 8;
    const int nb0 = bx * 10;
    const int rowblk0 = by * 8;

    // CVT staging geometry: thread covers units (tid) and (tid+256) of the
    // 8-tile A block: t = tid>>6 (+4), l = tid&63.
    const int ct = tid >> 6;          // == wv
    const int cl = tid & 63;
    const int crow0 = (rowblk0 + ct) * 16 + (cl & 15);       // for t = ct
    const int crow1 = (rowblk0 + ct + 4) * 16 + (cl & 15);   // for t = ct+4
    const int ckoff = (cl >> 4) * 8;

    f32x4 acc[2][10];
    #pragma unroll
    for (int r = 0; r < 2; ++r)
        #pragma unroll
        for (int c = 0; c < 10; ++c)
            acc[r][c] = (f32x4){0.f, 0.f, 0.f, 0.f};

    // ---- prologue: stage kt=0 into buffer 0 ----
    if (CVT_A) {
        #pragma unroll
        for (int j = 0; j < 2; ++j) {
            int row = j ? crow1 : crow0;
            int k0 = ckoff;                       // kt = 0
            uint4 o = {0u, 0u, 0u, 0u};
            if (k0 + 8 <= 376) {
                const float4* p = reinterpret_cast<const float4*>(
                    xf + (size_t)row * 376 + k0);
                float4 v0 = p[0], v1 = p[1];
                o.x = pack2(v0.x, v0.y); o.y = pack2(v0.z, v0.w);
                o.z = pack2(v1.x, v1.y); o.w = pack2(v1.z, v1.w);
            }
            *reinterpret_cast<uint4*>(&As[0][((ct + 4 * j) << 9) + (cl << 3)]) = o;
        }
    } else {
        #pragma unroll
        for (int i = 0; i < 2; ++i) {
            int t = wv * 2 + i;
            gl2lds16(At + (((size_t)(rowblk0 + t) * kTA + 0) << 9) + lane * 8,
                     &As[0][t << 9]);
        }
    }
    #pragma unroll
    for (int t2 = 0; t2 < 3; ++t2) {
        int t = wv + t2 * 4;
        if (t < 10)
            gl2lds16(Bt + (((size_t)(nb0 + t) * KITERS + 0) << 9) + lane * 8,
                     &Bs[0][t << 9]);
    }
    __syncthreads();

    // ---- main loop: compute buf p, stage kt+1 into buf p^1 ----
    #pragma unroll
    for (int kt = 0; kt < KITERS; ++kt) {
        const int p = kt & 1;
        uint4 nxt0, nxt1;
        if (kt + 1 < KITERS) {
            if (CVT_A) {
                // issue global f32 loads for kt+1 (held in regs)
                int k0 = (kt + 1) * 32 + ckoff;
                nxt0 = (uint4){0u, 0u, 0u, 0u};
                nxt1 = (uint4){0u, 0u, 0u, 0u};
                if (k0 + 8 <= 376) {
                    const float4* p0 = reinterpret_cast<const float4*>(
                        xf + (size_t)crow0 * 376 + k0);
                    float4 v0 = p0[0], v1 = p0[1];
                    nxt0.x = pack2(v0.x, v0.y); nxt0.y = pack2(v0.z, v0.w);
                    nxt0.z = pack2(v1.x, v1.y); nxt0.w = pack2(v1.z, v1.w);
                    const float4* p1 = reinterpret_cast<const float4*>(
                        xf + (size_t)crow1 * 376 + k0);
                    float4 u0 = p1[0], u1 = p1[1];
                    nxt1.x = pack2(u0.x, u0.y); nxt1.y = pack2(u0.z, u0.w);
                    nxt1.z = pack2(u1.x, u1.y); nxt1.w = pack2(u1.z, u1.w);
                }
            } else {
                #pragma unroll
                for (int i = 0; i < 2; ++i) {
                    int t = wv * 2 + i;
                    gl2lds16(At + (((size_t)(rowblk0 + t) * kTA + kt + 1) << 9) + lane * 8,
                             &As[p ^ 1][t << 9]);
                }
            }
            #pragma unroll
            for (int t2 = 0; t2 < 3; ++t2) {
                int t = wv + t2 * 4;
                if (t < 10)
                    gl2lds16(Bt + (((size_t)(nb0 + t) * KITERS + kt + 1) << 9) + lane * 8,
                             &Bs[p ^ 1][t << 9]);
            }
        }

        bf16x8 a0 = __builtin_bit_cast(bf16x8,
            *reinterpret_cast<const uint4*>(&As[p][((wv * 2 + 0) << 9) + lane * 8]));
        bf16x8 a1 = __builtin_bit_cast(bf16x8,
            *reinterpret_cast<const uint4*>(&As[p][((wv * 2 + 1) << 9) + lane * 8]));
        #pragma unroll
        for (int c = 0; c < 10; ++c) {
            bf16x8 bb = __builtin_bit_cast(bf16x8,
                *reinterpret_cast<const uint4*>(&Bs[p][(c << 9) + lane * 8]));
            acc[0][c] = __builtin_amdgcn_mfma_f32_16x16x32_bf16(a0, bb, acc[0][c], 0, 0, 0);
            acc[1][c] = __builtin_amdgcn_mfma_f32_16x16x32_bf16(a1, bb, acc[1][c], 0, 0, 0);
        }

        if (CVT_A && kt + 1 < KITERS) {
            *reinterpret_cast<uint4*>(&As[p ^ 1][(ct << 9) + (cl << 3)]) = nxt0;
            *reinterpret_cast<uint4*>(&As[p ^ 1][((ct + 4) << 9) + (cl << 3)]) = nxt1;
        }
        __syncthreads();
    }

    // ---- epilogue: bias + act -> tiled C; C/D frag: col=l16, row=q*4+reg ----
    #pragma unroll
    for (int r = 0; r < 2; ++r) {
        int rowblk = rowblk0 + wv * 2 + r;
        #pragma unroll
        for (int c = 0; c < 10; ++c) {
            int n = (nb0 + c) * 16 + l16;
            float bv = bias[n];
            #pragma unroll
            for (int reg = 0; reg < 4; ++reg) {
                float v = acc[r][c][reg] + bv;
                if (RELU) v = fmaxf(v, 0.f);
                int mrow = q * 4 + reg;
                size_t off = (((size_t)rowblk * kTC + (n >> 5)) << 9)
                           + (size_t)(((n >> 3) & 3) * 16 + mrow) * 8 + (n & 7);
                C[off] = f2bf(v);
            }
        }
    }
}

// ---------------------------------------------------------------------------
// flow_kernel v3: 4 lanes per row (lane sub owns head cols [8*sub, 8*sub+8)).
// Aligned 48-col u/w slots -> one uint4 per lane per vector, fully coalesced.
// Dots reduced across the 4-lane group via shfl_xor(1,2). No LDS, no spills.
// ---------------------------------------------------------------------------
__device__ inline void ld_group8(const ushort_t* hb, int g, float* dst) {
    uint4 v = *reinterpret_cast<const uint4*>(hb + ((g >> 2) << 9) + ((g & 3) << 7));
    unpack8(v, dst);
}

__global__ __launch_bounds__(256, 4)
void flow_kernel(const ushort_t* __restrict__ heads, const float* __restrict__ eps,
                 float* __restrict__ out, int Btot)
{
    const int tid = threadIdx.x;
    const int sub = tid & 3;
    const long row = (long)blockIdx.x * 64 + (tid >> 2);
    const ushort_t* hb = heads + (((size_t)(row >> 4) * KTH) << 9)
                               + (size_t)((row & 15) << 3);

    float z[8];
    float lp = 0.f;
    {
        float amu[8] = {0,0,0,0,0,0,0,0}, alv[8] = {0,0,0,0,0,0,0,0};
        if (sub < 3) {
            ld_group8(hb, sub, amu);
            ld_group8(hb, 3 + sub, alv);
        }
        float ep[8];
        #pragma unroll
        for (int c = 0; c < 8; ++c) {
            int i = sub * 8 + c;
            ep[c] = (i < 17) ? eps[row * 17 + i] : 0.f;
        }
        #pragma unroll
        for (int c = 0; c < 8; ++c) {
            float mu = fast_tanh(amu[c]);
            float lv = fast_tanh(alv[c]);
            z[c] = mu + __expf(lv) * ep[c];
            int i = sub * 8 + c;
            lp += (i < 17) ? (-0.5f * ep[c] * ep[c] - lv - 0.918938533f) : 0.f;
        }
    }

    float bv[16];
    ld_group8(hb, 6, &bv[0]);
    ld_group8(hb, 7, &bv[8]);

    float ldj = 0.f;
    #pragma unroll
    for (int k = 0; k < 15; ++k) {
        float au[8] = {0,0,0,0,0,0,0,0}, aw[8] = {0,0,0,0,0,0,0,0};
        if (sub < 3) {
            ld_group8(hb, 8 + 6 * k + sub, au);
            ld_group8(hb, 11 + 6 * k + sub, aw);
        }
        float uw = 0.f, w2 = 0.f, wz = 0.f;
        #pragma unroll
        for (int c = 0; c < 8; ++c) {
            uw += aw[c] * au[c];
            w2 += aw[c] * aw[c];
            wz += aw[c] * z[c];
        }
        uw += __shfl_xor(uw, 1); uw += __shfl_xor(uw, 2);
        w2 += __shfl_xor(w2, 1); w2 += __shfl_xor(w2, 2);
        wz += __shfl_xor(wz, 1); wz += __shfl_xor(wz, 2);

        float sp = (uw > 15.f) ? uw : __logf(1.f + __expf(uw));
        float m = sp - 1.f;                          // -1 + softplus(w.u)
        float coef = (m - uw) / fmaxf(w2, 1e-20f);
        float t = fast_tanh(wz + bv[k]);
        #pragma unroll
        for (int c = 0; c < 8; ++c)
            z[c] += (au[c] + coef * aw[c]) * t;
        float psi = m * (1.f - t * t);               // psi^T u_hat == m analytically
        ldj += __logf(fmaxf(fabsf(1.f + psi), 1e-30f));
    }

    lp += __shfl_xor(lp, 1); lp += __shfl_xor(lp, 2);
    #pragma unroll
    for (int c = 0; c < 8; ++c) {
        int i = sub * 8 + c;
        if (i < 17) out[row * 17 + i] = z[c];
    }
    float lpf = lp - ldj;
    if (sub == 0) {
        out[(long)Btot * 17 + row] = __expf(lpf);
        out[(long)Btot * 18 + row] = lpf;
    }
}

// ---------------------------------------------------------------------------
extern "C" void kernel_launch(void* const* d_in, const int* in_sizes, int n_in,
                              void* d_out, int out_size, void* d_ws, size_t ws_size,
                              hipStream_t stream)
{
    const float* x   = (const float*)d_in[0];
    const float* eps = (const float*)d_in[1];
    float* out = (float*)d_out;

    // ws layout (ushort units):
    //  [0, H2_US)                 h2' tiled (stride KTC2)
    //  [H2_US, H2_US+HEADS_US)    h1' tiled (stride KTC1, uses 31.5M) then
    //                             heads tiled (stride KTH, 52.4M) -- h1' dead
    //  weights after              (~1.15M us) + biases
    ushort_t* ws = (ushort_t*)d_ws;
    ushort_t* R_h2    = ws;
    ushort_t* R_h1    = ws + H2_US;
    ushort_t* R_heads = ws + H2_US;        // overlays h1'
    ushort_t* W1t = ws + H2_US + HEADS_US;
    ushort_t* W2t = W1t + SZ1;
    ushort_t* Wht = W2t + SZ2;
    float* b1p = (float*)(Wht + SZ3);
    float* b2p = b1p + 480;
    float* bHp = b2p + 320;

    const int packN = SZ1 + SZ2 + SZ3 + 1600;
    pack_kernel<<<(packN + 255) / 256, 256, 0, stream>>>(
        (const float*)d_in[2],  (const float*)d_in[4],
        (const float*)d_in[6],  (const float*)d_in[8],
        (const float*)d_in[10], (const float*)d_in[12], (const float*)d_in[14],
        (const float*)d_in[3],  (const float*)d_in[5],
        (const float*)d_in[7],  (const float*)d_in[9],
        (const float*)d_in[11], (const float*)d_in[13], (const float*)d_in[15],
        W1t, W2t, Wht, b1p, b2p, bHp);

    // K1: h1' = relu(x @ W1^T + b1), cvt fused.  M=65536 K=384 N=480
    gemm_db<KT1, 3, true, true><<<3 * 512, 256, 0, stream>>>(
        nullptr, x, W1t, b1p, R_h1, 0, KTC1);
    // K2: h2' = relu(h1' @ W2^T + b2).           M=65536 K=416 N=320
    gemm_db<KI2, 2, true, false><<<2 * 512, 256, 0, stream>>>(
        R_h1, nullptr, W2t, b2p, R_h2, KTC1, KTC2);
    // K3: heads = h2' @ Wh^T + bH.               M=65536 K=320 N=800
    gemm_db<KI3, 5, false, false><<<5 * 512, 256, 0, stream>>>(
        R_h2, nullptr, Wht, bHp, R_heads, KTC2, KTH);
    // K4: planar flow + log-prob
    flow_kernel<<<B_ROWS / 64, 256, 0, stream>>>(R_heads, eps, out, B_ROWS);
}